// Round 6
// baseline (286.535 us; speedup 1.0000x reference)
//
#include <hip/hip_runtime.h>
#include <cmath>

#define NN    4096
#define FIN   32
#define KSEL  39      // neighbors kept (top-40 minus self)
#define PP    22
#define PPAD  24
#define FOUT  48
#define WPB   2       // waves per block
#define CAP   256     // candidate overflow cap (degenerate data -> fallback)

typedef float v2f __attribute__((ext_vector_type(2)));

#define WSYNC() asm volatile("s_waitcnt lgkmcnt(0)" ::: "memory")

// ---------------- precompute: one thread per point -------------------------------
// feats = x@Wf+bf (padded to 24), coords in element layout (for cq) AND pair-SoA
// layout [x0,x1,y0,y1,z0,z1,w0,w1] (for the packed scan).
__global__ __launch_bounds__(64) void gn_pre(
    const float* __restrict__ x,
    const float* __restrict__ Wf, const float* __restrict__ bf,
    const float* __restrict__ Ws, const float* __restrict__ bs,
    float* __restrict__ coords4, float* __restrict__ cpair, float* __restrict__ feats)
{
    int p = blockIdx.x * 64 + threadIdx.x;

    const float4* xr4 = (const float4*)(x + (size_t)p * FIN);
    float xv[FIN];
    #pragma unroll
    for (int i = 0; i < 8; ++i) {
        float4 t = xr4[i];
        xv[4*i] = t.x; xv[4*i+1] = t.y; xv[4*i+2] = t.z; xv[4*i+3] = t.w;
    }

    float fa[PP];
    #pragma unroll
    for (int c = 0; c < PP; ++c) fa[c] = bf[c];
    #pragma unroll
    for (int i = 0; i < FIN; ++i) {
        float xi = xv[i];
        #pragma unroll
        for (int c = 0; c < PP; ++c) fa[c] = fmaf(xi, Wf[i * PP + c], fa[c]);
    }

    float ca[4];
    #pragma unroll
    for (int c = 0; c < 4; ++c) ca[c] = bs[c];
    #pragma unroll
    for (int i = 0; i < FIN; ++i) {
        float xi = xv[i];
        #pragma unroll
        for (int c = 0; c < 4; ++c) ca[c] = fmaf(xi, Ws[i * 4 + c], ca[c]);
    }

    float4* fw = (float4*)(feats + (size_t)p * PPAD);
    fw[0] = make_float4(fa[0],  fa[1],  fa[2],  fa[3]);
    fw[1] = make_float4(fa[4],  fa[5],  fa[6],  fa[7]);
    fw[2] = make_float4(fa[8],  fa[9],  fa[10], fa[11]);
    fw[3] = make_float4(fa[12], fa[13], fa[14], fa[15]);
    fw[4] = make_float4(fa[16], fa[17], fa[18], fa[19]);
    fw[5] = make_float4(fa[20], fa[21], 0.f, 0.f);

    ((float4*)coords4)[p] = make_float4(ca[0], ca[1], ca[2], ca[3]);

    int pr = p >> 1, sl = p & 1;
    float* cp = cpair + (size_t)pr * 8 + sl;
    cp[0] = ca[0]; cp[2] = ca[1]; cp[4] = ca[2]; cp[6] = ca[3];
}

// full 64-lane bitonic sort, float keys, ascending
__device__ __forceinline__ float sortf64(float v, int lane) {
    #pragma unroll
    for (int k = 2; k <= 64; k <<= 1) {
        #pragma unroll
        for (int j = k >> 1; j >= 1; j >>= 1) {
            float ov = __shfl_xor(v, j);
            bool keepMin = (((lane & j) == 0) == ((lane & k) == 0));
            bool less = ov < v;
            v = (less == keepMin) ? ov : v;
        }
    }
    return v;
}

// full 64-lane bitonic sort of (float d2, int idx), ascending lexicographic
__device__ __forceinline__ void sort64_pair(float& v, int& m, int lane) {
    #pragma unroll
    for (int k = 2; k <= 64; k <<= 1) {
        #pragma unroll
        for (int j = k >> 1; j >= 1; j >>= 1) {
            float ov = __shfl_xor(v, j);
            int   om = __shfl_xor(m, j);
            bool keepMin = (((lane & j) == 0) == ((lane & k) == 0));
            bool less = (ov < v) || (ov == v && om < m);
            bool take = (less == keepMin);
            v = take ? ov : v;
            m = take ? om : m;
        }
    }
}

// merge sorted-ascending running list with sorted-ascending chunk; keep 64 smallest
__device__ __forceinline__ void merge64(float& Lv, int& Lm, float cv, int cm, int lane) {
    float rv = __shfl_xor(cv, 63);
    int   rm = __shfl_xor(cm, 63);
    bool less = (rv < Lv) || (rv == Lv && rm < Lm);
    if (less) { Lv = rv; Lm = rm; }
    #pragma unroll
    for (int j = 32; j >= 1; j >>= 1) {
        float ov = __shfl_xor(Lv, j);
        int   om = __shfl_xor(Lm, j);
        bool lower = ((lane & j) == 0);
        bool l2 = (ov < Lv) || (ov == Lv && om < Lm);
        bool take = (l2 == lower);
        Lv = take ? ov : Lv;
        Lm = take ? om : Lm;
    }
}

// ---------------- main: one wave per query ---------------------------------------
__global__ __launch_bounds__(WPB * 64, 4) void gn_main(
    const float* __restrict__ x,
    const float* __restrict__ Wo, const float* __restrict__ bo,
    const float* __restrict__ coords4, const float* __restrict__ cpair,
    const float* __restrict__ feats,
    float* __restrict__ out)
{
    __shared__ unsigned sel_s[WPB * CAP * 2];            // (d2 bits, idx) pairs
    __shared__ float fstage_s[WPB * KSEL * PPAD];
    __shared__ float agg_s[WPB * 48];

    const float INF = __builtin_inff();
    const float NEGINF = -INF;
    const int wv   = threadIdx.x >> 6;
    const int lane = threadIdx.x & 63;
    const int q    = blockIdx.x * WPB + wv;
    const int b    = q >> 12;
    const int n    = q & (NN - 1);
    unsigned* sel    = sel_s + wv * CAP * 2;
    float*    fstage = fstage_s + wv * (KSEL * PPAD);
    float*    agg    = agg_s + wv * 48;

    const float4* c4  = ((const float4*)coords4) + (size_t)b * NN;
    // cpair: per batch NN/2 pairs x 2 float4 = NN float4s  -> base is b*NN
    const float4* cp4 = ((const float4*)cpair) + (size_t)b * NN;

    float4 cq = c4[n];
    float  sqn = fmaf(cq.x, cq.x, fmaf(cq.y, cq.y, fmaf(cq.z, cq.z, cq.w * cq.w)));
    float4 m2 = make_float4(-2.f * cq.x, -2.f * cq.y, -2.f * cq.z, -2.f * cq.w);
    v2f sqn2 = {sqn, sqn};
    v2f m2x = {m2.x, m2.x}, m2y = {m2.y, m2.y}, m2z = {m2.z, m2.z}, m2w = {m2.w, m2.w};

    // ---- pass 1: packed d2 for 2 elems/iter, cached in regs; self INCLUDED ----
    v2f d2c[32];
    v2f kmin2 = {INF, INF};
    #pragma unroll
    for (int i = 0; i < 32; ++i) {
        int pr = i * 64 + lane;
        float4 A  = cp4[2 * pr];         // x0,x1,y0,y1
        float4 Bv = cp4[2 * pr + 1];     // z0,z1,w0,w1
        v2f xs = {A.x,  A.y},  ys = {A.z,  A.w};
        v2f zs = {Bv.x, Bv.y}, ws = {Bv.z, Bv.w};
        v2f acc = __builtin_elementwise_fma(xs, xs + m2x, sqn2);
        acc = __builtin_elementwise_fma(ys, ys + m2y, acc);
        acc = __builtin_elementwise_fma(zs, zs + m2z, acc);
        acc = __builtin_elementwise_fma(ws, ws + m2w, acc);
        d2c[i] = acc;
        kmin2 = __builtin_elementwise_min(kmin2, acc);
    }
    float kmin = fminf(kmin2.x, kmin2.y);

    // ---- bound: UB = 40th smallest of 64 lane minima (covers self) ----
    float smin = sortf64(kmin, lane);
    float UB = __shfl(smin, KSEL);

    // ---- compact candidates {d2 <= UB, m != n} from registers ----
    const unsigned long long lt = (1ull << lane) - 1ull;
    int C = 0;
    #pragma unroll
    for (int i = 0; i < 32; ++i) {
        int pr = i * 64 + lane;
        int m0 = 2 * pr, m1 = 2 * pr + 1;
        v2f d = d2c[i];
        bool p0 = (d.x <= UB) && (m0 != n);
        bool p1 = (d.y <= UB) && (m1 != n);
        unsigned long long b0 = __ballot(p0); int c0 = (int)__popcll(b0);
        unsigned long long b1 = __ballot(p1);
        if (p0) { int s = C +      (int)__popcll(b0 & lt); if (s < CAP) { sel[2*s] = __float_as_uint(d.x); sel[2*s+1] = (unsigned)m0; } }
        if (p1) { int s = C + c0 + (int)__popcll(b1 & lt); if (s < CAP) { sel[2*s] = __float_as_uint(d.y); sel[2*s+1] = (unsigned)m1; } }
        C += c0 + (int)__popcll(b1);
    }
    WSYNC();

    // ---- exact top-39 by (d2, idx): bitonic sort chunks + merge ----
    float Lv = INF; int Lm = 0x7FFFFFFF;
    if (C <= CAP) {
        int nch = (C + 63) >> 6;
        for (int c = 0; c < nch; ++c) {
            int s = c * 64 + lane;
            float v; int m;
            if (s < C) { v = __uint_as_float(sel[2*s]); m = (int)sel[2*s+1]; }
            else       { v = INF; m = 0x7FFFFFFF; }
            sort64_pair(v, m, lane);
            if (c == 0) { Lv = v; Lm = m; }
            else        merge64(Lv, Lm, v, m, lane);
        }
    } else {
        // degenerate fallback: exact streaming top-64 over all 4096
        for (int c = 0; c < 64; ++c) {
            int m = c * 64 + lane;
            int pr = m >> 1, sl = m & 1;
            float4 A = cp4[2 * pr], Bv = cp4[2 * pr + 1];
            float cx = sl ? A.y  : A.x,  cy = sl ? A.w  : A.z;
            float cz = sl ? Bv.y : Bv.x, cw = sl ? Bv.w : Bv.z;
            float v = sqn;
            v = fmaf(cx, cx + m2.x, v);
            v = fmaf(cy, cy + m2.y, v);
            v = fmaf(cz, cz + m2.z, v);
            v = fmaf(cw, cw + m2.w, v);
            if (m == n) v = INF;
            sort64_pair(v, m, lane);
            if (c == 0) { Lv = v; Lm = m; }
            else        merge64(Lv, Lm, v, m, lane);
        }
    }
    // lanes 0..38 hold the 39 nearest (d2 ascending, index tie-break)

    // ---- weighted features -> LDS [39][24] ----
    if (lane < KSEL) {
        float wgt = __expf(-fabsf(10.f * Lv));
        const float4* fr = (const float4*)(feats + ((size_t)b * NN + Lm) * PPAD);
        float4 f0 = fr[0], f1 = fr[1], f2 = fr[2], f3 = fr[3], f4 = fr[4], f5 = fr[5];
        float4* row = (float4*)(fstage + lane * PPAD);
        row[0] = make_float4(f0.x * wgt, f0.y * wgt, f0.z * wgt, f0.w * wgt);
        row[1] = make_float4(f1.x * wgt, f1.y * wgt, f1.z * wgt, f1.w * wgt);
        row[2] = make_float4(f2.x * wgt, f2.y * wgt, f2.z * wgt, f2.w * wgt);
        row[3] = make_float4(f3.x * wgt, f3.y * wgt, f3.z * wgt, f3.w * wgt);
        row[4] = make_float4(f4.x * wgt, f4.y * wgt, f4.z * wgt, f4.w * wgt);
        row[5] = make_float4(f5.x * wgt, f5.y * wgt, f5.z * wgt, f5.w * wgt);
    }
    WSYNC();

    // ---- max / mean over 39 neighbors (lanes 0..21) ----
    if (lane < PP) {
        float mx = NEGINF, sm = 0.f;
        for (int k = 0; k < KSEL; ++k) {
            float v = fstage[k * PPAD + lane];
            mx = fmaxf(mx, v);
            sm += v;
        }
        agg[lane]      = mx;
        agg[PP + lane] = sm * (1.f / (float)KSEL);
    }
    WSYNC();

    // ---- epilogue: out = tanh([x | max | mean] @ Wo + bo), fast tanh ----
    if (lane < FOUT) {
        const float* xr = x + (size_t)q * FIN;
        float acc = bo[lane];
        #pragma unroll
        for (int f = 0; f < FIN; ++f)
            acc = fmaf(xr[f], Wo[f * FOUT + lane], acc);
        #pragma unroll
        for (int f = 0; f < 2 * PP; ++f)
            acc = fmaf(agg[f], Wo[(FIN + f) * FOUT + lane], acc);
        float e = __expf(2.f * acc);
        float r = __builtin_amdgcn_rcpf(e + 1.f);
        out[(size_t)q * FOUT + lane] = fmaf(-2.f, r, 1.f);
    }
}

extern "C" void kernel_launch(void* const* d_in, const int* in_sizes, int n_in,
                              void* d_out, int out_size, void* d_ws, size_t ws_size,
                              hipStream_t stream) {
    const float* x  = (const float*)d_in[0];
    const float* Wf = (const float*)d_in[1];
    const float* bf = (const float*)d_in[2];
    const float* Ws = (const float*)d_in[3];
    const float* bs = (const float*)d_in[4];
    const float* Wo = (const float*)d_in[5];
    const float* bo = (const float*)d_in[6];
    float* outp = (float*)d_out;

    float* ws      = (float*)d_ws;
    float* coords4 = ws;                      // 32768*4  = 131072 floats
    float* cpair   = ws + 131072;             // 32768*4  = 131072 floats (pair-SoA)
    float* feats   = ws + 262144;             // 32768*24 = 786432 floats

    gn_pre<<<32768 / 64, 64, 0, stream>>>(x, Wf, bf, Ws, bs, coords4, cpair, feats);
    gn_main<<<32768 / WPB, WPB * 64, 0, stream>>>(x, Wo, bo, coords4, cpair, feats, outp);
}

// Round 7
// 251.639 us; speedup vs baseline: 1.1387x; 1.1387x over previous
//
#include <hip/hip_runtime.h>
#include <cmath>

#define NN    4096
#define FIN   32
#define KSEL  39      // neighbors kept (top-40 minus self)
#define PP    22
#define PPAD  24
#define FOUT  48
#define WPB   2       // waves per block
#define CAP   256     // candidate overflow cap (degenerate data -> fallback)

typedef float v2f __attribute__((ext_vector_type(2)));

#define WSYNC() asm volatile("s_waitcnt lgkmcnt(0)" ::: "memory")

// ---------------- precompute: one thread per point -------------------------------
// feats = x@Wf+bf (padded to 24), coords in element layout (for cq) AND pair-SoA
// layout [x0,x1,y0,y1,z0,z1,w0,w1] (for the packed scan).
__global__ __launch_bounds__(64) void gn_pre(
    const float* __restrict__ x,
    const float* __restrict__ Wf, const float* __restrict__ bf,
    const float* __restrict__ Ws, const float* __restrict__ bs,
    float* __restrict__ coords4, float* __restrict__ cpair, float* __restrict__ feats)
{
    int p = blockIdx.x * 64 + threadIdx.x;

    const float4* xr4 = (const float4*)(x + (size_t)p * FIN);
    float xv[FIN];
    #pragma unroll
    for (int i = 0; i < 8; ++i) {
        float4 t = xr4[i];
        xv[4*i] = t.x; xv[4*i+1] = t.y; xv[4*i+2] = t.z; xv[4*i+3] = t.w;
    }

    float fa[PP];
    #pragma unroll
    for (int c = 0; c < PP; ++c) fa[c] = bf[c];
    #pragma unroll
    for (int i = 0; i < FIN; ++i) {
        float xi = xv[i];
        #pragma unroll
        for (int c = 0; c < PP; ++c) fa[c] = fmaf(xi, Wf[i * PP + c], fa[c]);
    }

    float ca[4];
    #pragma unroll
    for (int c = 0; c < 4; ++c) ca[c] = bs[c];
    #pragma unroll
    for (int i = 0; i < FIN; ++i) {
        float xi = xv[i];
        #pragma unroll
        for (int c = 0; c < 4; ++c) ca[c] = fmaf(xi, Ws[i * 4 + c], ca[c]);
    }

    float4* fw = (float4*)(feats + (size_t)p * PPAD);
    fw[0] = make_float4(fa[0],  fa[1],  fa[2],  fa[3]);
    fw[1] = make_float4(fa[4],  fa[5],  fa[6],  fa[7]);
    fw[2] = make_float4(fa[8],  fa[9],  fa[10], fa[11]);
    fw[3] = make_float4(fa[12], fa[13], fa[14], fa[15]);
    fw[4] = make_float4(fa[16], fa[17], fa[18], fa[19]);
    fw[5] = make_float4(fa[20], fa[21], 0.f, 0.f);

    ((float4*)coords4)[p] = make_float4(ca[0], ca[1], ca[2], ca[3]);

    int pr = p >> 1, sl = p & 1;
    float* cp = cpair + (size_t)pr * 8 + sl;
    cp[0] = ca[0]; cp[2] = ca[1]; cp[4] = ca[2]; cp[6] = ca[3];
}

// full 64-lane bitonic sort, float keys, ascending
__device__ __forceinline__ float sortf64(float v, int lane) {
    #pragma unroll
    for (int k = 2; k <= 64; k <<= 1) {
        #pragma unroll
        for (int j = k >> 1; j >= 1; j >>= 1) {
            float ov = __shfl_xor(v, j);
            bool keepMin = (((lane & j) == 0) == ((lane & k) == 0));
            bool less = ov < v;
            v = (less == keepMin) ? ov : v;
        }
    }
    return v;
}

// full 64-lane bitonic sort of (float d2, int idx), ascending lexicographic
__device__ __forceinline__ void sort64_pair(float& v, int& m, int lane) {
    #pragma unroll
    for (int k = 2; k <= 64; k <<= 1) {
        #pragma unroll
        for (int j = k >> 1; j >= 1; j >>= 1) {
            float ov = __shfl_xor(v, j);
            int   om = __shfl_xor(m, j);
            bool keepMin = (((lane & j) == 0) == ((lane & k) == 0));
            bool less = (ov < v) || (ov == v && om < m);
            bool take = (less == keepMin);
            v = take ? ov : v;
            m = take ? om : m;
        }
    }
}

// merge sorted-ascending running list with sorted-ascending chunk; keep 64 smallest
__device__ __forceinline__ void merge64(float& Lv, int& Lm, float cv, int cm, int lane) {
    float rv = __shfl_xor(cv, 63);
    int   rm = __shfl_xor(cm, 63);
    bool less = (rv < Lv) || (rv == Lv && rm < Lm);
    if (less) { Lv = rv; Lm = rm; }
    #pragma unroll
    for (int j = 32; j >= 1; j >>= 1) {
        float ov = __shfl_xor(Lv, j);
        int   om = __shfl_xor(Lm, j);
        bool lower = ((lane & j) == 0);
        bool l2 = (ov < Lv) || (ov == Lv && om < Lm);
        bool take = (l2 == lower);
        Lv = take ? ov : Lv;
        Lm = take ? om : Lm;
    }
}

// ---------------- main: one wave per query ---------------------------------------
__global__ __launch_bounds__(WPB * 64, 5) void gn_main(
    const float* __restrict__ x,
    const float* __restrict__ Wo, const float* __restrict__ bo,
    const float* __restrict__ coords4, const float* __restrict__ cpair,
    const float* __restrict__ feats,
    float* __restrict__ out)
{
    __shared__ unsigned long long sel_s[WPB * CAP];      // (d2bits<<32)|idx
    __shared__ float fstage_s[WPB * KSEL * PPAD];
    __shared__ float agg_s[WPB * 48];
    __shared__ unsigned cnt_s[WPB];

    const float INF = __builtin_inff();
    const float NEGINF = -INF;
    const int wv   = threadIdx.x >> 6;
    const int lane = threadIdx.x & 63;
    const int q    = blockIdx.x * WPB + wv;
    const int b    = q >> 12;
    const int n    = q & (NN - 1);
    unsigned long long* sel = sel_s + wv * CAP;
    float* fstage = fstage_s + wv * (KSEL * PPAD);
    float* agg    = agg_s + wv * 48;

    const float4* c4  = ((const float4*)coords4) + (size_t)b * NN;
    const float4* cp4 = ((const float4*)cpair) + (size_t)b * NN;   // NN float4 per batch

    float4 cq = c4[n];
    float  sqn = fmaf(cq.x, cq.x, fmaf(cq.y, cq.y, fmaf(cq.z, cq.z, cq.w * cq.w)));
    float4 m2 = make_float4(-2.f * cq.x, -2.f * cq.y, -2.f * cq.z, -2.f * cq.w);
    v2f sqn2 = {sqn, sqn};
    v2f zero2 = {0.f, 0.f};
    v2f m2x = {m2.x, m2.x}, m2y = {m2.y, m2.y}, m2z = {m2.z, m2.z}, m2w = {m2.w, m2.w};

    if (lane == 0) cnt_s[wv] = 0;

    // ---- pass 1: packed d2 (clamped >= 0), per-lane min; self INCLUDED ----
    v2f kmin2 = {INF, INF};
    #pragma unroll 4
    for (int i = 0; i < 32; ++i) {
        int pr = i * 64 + lane;
        float4 A  = cp4[2 * pr];         // x0,x1,y0,y1
        float4 Bv = cp4[2 * pr + 1];     // z0,z1,w0,w1
        v2f xs = {A.x,  A.y},  ys = {A.z,  A.w};
        v2f zs = {Bv.x, Bv.y}, ws = {Bv.z, Bv.w};
        v2f acc = __builtin_elementwise_fma(xs, xs + m2x, sqn2);
        acc = __builtin_elementwise_fma(ys, ys + m2y, acc);
        acc = __builtin_elementwise_fma(zs, zs + m2z, acc);
        acc = __builtin_elementwise_fma(ws, ws + m2w, acc);
        acc = __builtin_elementwise_max(acc, zero2);
        kmin2 = __builtin_elementwise_min(kmin2, acc);
    }
    float kmin = fminf(kmin2.x, kmin2.y);

    // ---- bound: UB = 40th smallest of 64 lane minima (covers self) ----
    float smin = sortf64(kmin, lane);
    float UB = __shfl(smin, KSEL);
    WSYNC();   // cnt_s init visible

    // ---- compact candidates {d2 <= UB, m != n}: LDS-atomic slot alloc ----
    #pragma unroll 4
    for (int i = 0; i < 32; ++i) {
        int pr = i * 64 + lane;
        float4 A  = cp4[2 * pr];
        float4 Bv = cp4[2 * pr + 1];
        v2f xs = {A.x,  A.y},  ys = {A.z,  A.w};
        v2f zs = {Bv.x, Bv.y}, ws = {Bv.z, Bv.w};
        v2f acc = __builtin_elementwise_fma(xs, xs + m2x, sqn2);
        acc = __builtin_elementwise_fma(ys, ys + m2y, acc);
        acc = __builtin_elementwise_fma(zs, zs + m2z, acc);
        acc = __builtin_elementwise_fma(ws, ws + m2w, acc);
        acc = __builtin_elementwise_max(acc, zero2);
        int m0 = 2 * pr, m1 = 2 * pr + 1;
        bool p0 = (acc.x <= UB) & (m0 != n);
        bool p1 = (acc.y <= UB) & (m1 != n);
        if (p0 || p1) {
            unsigned s = atomicAdd(&cnt_s[wv], (unsigned)((int)p0 + (int)p1));
            if (p0 && s < CAP)
                sel[s] = (((unsigned long long)__float_as_uint(acc.x)) << 32) | (unsigned)m0;
            unsigned s1 = s + (p0 ? 1u : 0u);
            if (p1 && s1 < CAP)
                sel[s1] = (((unsigned long long)__float_as_uint(acc.y)) << 32) | (unsigned)m1;
        }
    }
    WSYNC();
    int C = (int)cnt_s[wv];

    // ---- exact top-39 by (d2, idx): bitonic sort chunks + merge ----
    float Lv = INF; int Lm = 0x7FFFFFFF;
    if (C <= CAP) {
        int nch = (C + 63) >> 6;
        for (int c = 0; c < nch; ++c) {
            int s = c * 64 + lane;
            float v; int m;
            if (s < C) {
                unsigned long long e = sel[s];
                v = __uint_as_float((unsigned)(e >> 32));
                m = (int)(unsigned)(e & 0xFFFFFFFFu);
            } else { v = INF; m = 0x7FFFFFFF; }
            sort64_pair(v, m, lane);
            if (c == 0) { Lv = v; Lm = m; }
            else        merge64(Lv, Lm, v, m, lane);
        }
    } else {
        // degenerate fallback: exact streaming top-64 over all 4096
        for (int c = 0; c < 64; ++c) {
            int m = c * 64 + lane;
            int pr = m >> 1, sl = m & 1;
            float4 A = cp4[2 * pr], Bv = cp4[2 * pr + 1];
            float cx = sl ? A.y  : A.x,  cy = sl ? A.w  : A.z;
            float cz = sl ? Bv.y : Bv.x, cw = sl ? Bv.w : Bv.z;
            float v = sqn;
            v = fmaf(cx, cx + m2.x, v);
            v = fmaf(cy, cy + m2.y, v);
            v = fmaf(cz, cz + m2.z, v);
            v = fmaf(cw, cw + m2.w, v);
            v = fmaxf(v, 0.f);
            if (m == n) v = INF;
            sort64_pair(v, m, lane);
            if (c == 0) { Lv = v; Lm = m; }
            else        merge64(Lv, Lm, v, m, lane);
        }
    }
    // lanes 0..38 hold the 39 nearest (d2 ascending, index tie-break)

    // ---- weighted features -> LDS [39][24] ----
    if (lane < KSEL) {
        float wgt = __expf(-fabsf(10.f * Lv));
        const float4* fr = (const float4*)(feats + ((size_t)b * NN + Lm) * PPAD);
        float4 f0 = fr[0], f1 = fr[1], f2 = fr[2], f3 = fr[3], f4 = fr[4], f5 = fr[5];
        float4* row = (float4*)(fstage + lane * PPAD);
        row[0] = make_float4(f0.x * wgt, f0.y * wgt, f0.z * wgt, f0.w * wgt);
        row[1] = make_float4(f1.x * wgt, f1.y * wgt, f1.z * wgt, f1.w * wgt);
        row[2] = make_float4(f2.x * wgt, f2.y * wgt, f2.z * wgt, f2.w * wgt);
        row[3] = make_float4(f3.x * wgt, f3.y * wgt, f3.z * wgt, f3.w * wgt);
        row[4] = make_float4(f4.x * wgt, f4.y * wgt, f4.z * wgt, f4.w * wgt);
        row[5] = make_float4(f5.x * wgt, f5.y * wgt, f5.z * wgt, f5.w * wgt);
    }
    WSYNC();

    // ---- max / mean over 39 neighbors (lanes 0..21) ----
    if (lane < PP) {
        float mx = NEGINF, sm = 0.f;
        for (int k = 0; k < KSEL; ++k) {
            float v = fstage[k * PPAD + lane];
            mx = fmaxf(mx, v);
            sm += v;
        }
        agg[lane]      = mx;
        agg[PP + lane] = sm * (1.f / (float)KSEL);
    }
    WSYNC();

    // ---- epilogue: out = tanh([x | max | mean] @ Wo + bo), fast tanh ----
    if (lane < FOUT) {
        const float* xr = x + (size_t)q * FIN;
        float acc = bo[lane];
        #pragma unroll
        for (int f = 0; f < FIN; ++f)
            acc = fmaf(xr[f], Wo[f * FOUT + lane], acc);
        #pragma unroll
        for (int f = 0; f < 2 * PP; ++f)
            acc = fmaf(agg[f], Wo[(FIN + f) * FOUT + lane], acc);
        float e = __expf(2.f * acc);
        float r = __builtin_amdgcn_rcpf(e + 1.f);
        out[(size_t)q * FOUT + lane] = fmaf(-2.f, r, 1.f);
    }
}

extern "C" void kernel_launch(void* const* d_in, const int* in_sizes, int n_in,
                              void* d_out, int out_size, void* d_ws, size_t ws_size,
                              hipStream_t stream) {
    const float* x  = (const float*)d_in[0];
    const float* Wf = (const float*)d_in[1];
    const float* bf = (const float*)d_in[2];
    const float* Ws = (const float*)d_in[3];
    const float* bs = (const float*)d_in[4];
    const float* Wo = (const float*)d_in[5];
    const float* bo = (const float*)d_in[6];
    float* outp = (float*)d_out;

    float* ws      = (float*)d_ws;
    float* coords4 = ws;                      // 32768*4  = 131072 floats
    float* cpair   = ws + 131072;             // 32768*4  = 131072 floats (pair-SoA)
    float* feats   = ws + 262144;             // 32768*24 = 786432 floats

    gn_pre<<<32768 / 64, 64, 0, stream>>>(x, Wf, bf, Ws, bs, coords4, cpair, feats);
    gn_main<<<32768 / WPB, WPB * 64, 0, stream>>>(x, Wo, bo, coords4, cpair, feats, outp);
}

// Round 8
// 249.171 us; speedup vs baseline: 1.1499x; 1.0099x over previous
//
#include <hip/hip_runtime.h>
#include <cmath>

#define NN    4096
#define FIN   32
#define KSEL  39      // neighbors kept (top-40 minus self)
#define PP    22
#define PPAD  24
#define FOUT  48
#define WPB   2       // waves per block
#define CAP   256     // candidate overflow cap (degenerate data -> fallback)

typedef float v2f __attribute__((ext_vector_type(2)));

#define WSYNC() asm volatile("s_waitcnt lgkmcnt(0)" ::: "memory")

// ---------------- precompute: one thread per point -------------------------------
__global__ __launch_bounds__(256) void gn_pre(
    const float* __restrict__ x,
    const float* __restrict__ Wf, const float* __restrict__ bf,
    const float* __restrict__ Ws, const float* __restrict__ bs,
    float* __restrict__ coords4, float* __restrict__ cpair, float* __restrict__ feats)
{
    int p = blockIdx.x * 256 + threadIdx.x;

    const float4* xr4 = (const float4*)(x + (size_t)p * FIN);
    float xv[FIN];
    #pragma unroll
    for (int i = 0; i < 8; ++i) {
        float4 t = xr4[i];
        xv[4*i] = t.x; xv[4*i+1] = t.y; xv[4*i+2] = t.z; xv[4*i+3] = t.w;
    }

    float fa[PP];
    #pragma unroll
    for (int c = 0; c < PP; ++c) fa[c] = bf[c];
    #pragma unroll
    for (int i = 0; i < FIN; ++i) {
        float xi = xv[i];
        #pragma unroll
        for (int c = 0; c < PP; ++c) fa[c] = fmaf(xi, Wf[i * PP + c], fa[c]);
    }

    float ca[4];
    #pragma unroll
    for (int c = 0; c < 4; ++c) ca[c] = bs[c];
    #pragma unroll
    for (int i = 0; i < FIN; ++i) {
        float xi = xv[i];
        #pragma unroll
        for (int c = 0; c < 4; ++c) ca[c] = fmaf(xi, Ws[i * 4 + c], ca[c]);
    }

    float4* fw = (float4*)(feats + (size_t)p * PPAD);
    fw[0] = make_float4(fa[0],  fa[1],  fa[2],  fa[3]);
    fw[1] = make_float4(fa[4],  fa[5],  fa[6],  fa[7]);
    fw[2] = make_float4(fa[8],  fa[9],  fa[10], fa[11]);
    fw[3] = make_float4(fa[12], fa[13], fa[14], fa[15]);
    fw[4] = make_float4(fa[16], fa[17], fa[18], fa[19]);
    fw[5] = make_float4(fa[20], fa[21], 0.f, 0.f);

    ((float4*)coords4)[p] = make_float4(ca[0], ca[1], ca[2], ca[3]);

    int pr = p >> 1, sl = p & 1;
    float* cp = cpair + (size_t)pr * 8 + sl;
    cp[0] = ca[0]; cp[2] = ca[1]; cp[4] = ca[2]; cp[6] = ca[3];
}

// ---- fallback-only helpers (degenerate C > CAP path) ----------------------------
__device__ __forceinline__ void sort64_pair(float& v, int& m, int lane) {
    #pragma unroll
    for (int k = 2; k <= 64; k <<= 1) {
        #pragma unroll
        for (int j = k >> 1; j >= 1; j >>= 1) {
            float ov = __shfl_xor(v, j);
            int   om = __shfl_xor(m, j);
            bool keepMin = (((lane & j) == 0) == ((lane & k) == 0));
            bool less = (ov < v) || (ov == v && om < m);
            bool take = (less == keepMin);
            v = take ? ov : v;
            m = take ? om : m;
        }
    }
}
__device__ __forceinline__ void merge64(float& Lv, int& Lm, float cv, int cm, int lane) {
    float rv = __shfl_xor(cv, 63);
    int   rm = __shfl_xor(cm, 63);
    bool less = (rv < Lv) || (rv == Lv && rm < Lm);
    if (less) { Lv = rv; Lm = rm; }
    #pragma unroll
    for (int j = 32; j >= 1; j >>= 1) {
        float ov = __shfl_xor(Lv, j);
        int   om = __shfl_xor(Lm, j);
        bool lower = ((lane & j) == 0);
        bool l2 = (ov < Lv) || (ov == Lv && om < Lm);
        bool take = (l2 == lower);
        Lv = take ? ov : Lv;
        Lm = take ? om : Lm;
    }
}

// ---------------- main: one wave per query ---------------------------------------
__global__ __launch_bounds__(WPB * 64, 5) void gn_main(
    const float* __restrict__ x,
    const float* __restrict__ Wo, const float* __restrict__ bo,
    const float* __restrict__ coords4, const float* __restrict__ cpair,
    const float* __restrict__ feats,
    float* __restrict__ out)
{
    __shared__ unsigned long long sel_s[WPB * CAP];      // (d2bits<<32)|idx
    __shared__ float fstage_s[WPB * KSEL * PPAD];
    __shared__ float agg_s[WPB * 48];
    __shared__ unsigned cnt_s[WPB];
    __shared__ unsigned cnt2_s[WPB];

    const float INF = __builtin_inff();
    const float NEGINF = -INF;
    const int wv   = threadIdx.x >> 6;
    const int lane = threadIdx.x & 63;
    const int q    = blockIdx.x * WPB + wv;
    const int b    = q >> 12;
    const int n    = q & (NN - 1);
    unsigned long long* sel = sel_s + wv * CAP;
    float* fstage = fstage_s + wv * (KSEL * PPAD);
    float* agg    = agg_s + wv * 48;

    const float4* c4  = ((const float4*)coords4) + (size_t)b * NN;
    const float4* cp4 = ((const float4*)cpair) + (size_t)b * NN;   // NN float4 per batch

    float4 cq = c4[n];
    float  sqn = fmaf(cq.x, cq.x, fmaf(cq.y, cq.y, fmaf(cq.z, cq.z, cq.w * cq.w)));
    float4 m2 = make_float4(-2.f * cq.x, -2.f * cq.y, -2.f * cq.z, -2.f * cq.w);
    v2f sqn2 = {sqn, sqn};
    v2f zero2 = {0.f, 0.f};
    v2f m2x = {m2.x, m2.x}, m2y = {m2.y, m2.y}, m2z = {m2.z, m2.z}, m2w = {m2.w, m2.w};

    if (lane == 0) { cnt_s[wv] = 0; cnt2_s[wv] = 0; }

    // ---- pass 1: packed d2, per-lane running min; self INCLUDED ----
    v2f kmin2 = {INF, INF};
    #pragma unroll 4
    for (int i = 0; i < 32; ++i) {
        int pr = i * 64 + lane;
        float4 A  = cp4[2 * pr];         // x0,x1,y0,y1
        float4 Bv = cp4[2 * pr + 1];     // z0,z1,w0,w1
        v2f xs = {A.x,  A.y},  ys = {A.z,  A.w};
        v2f zs = {Bv.x, Bv.y}, ws = {Bv.z, Bv.w};
        v2f acc = __builtin_elementwise_fma(xs, xs + m2x, sqn2);
        acc = __builtin_elementwise_fma(ys, ys + m2y, acc);
        acc = __builtin_elementwise_fma(zs, zs + m2z, acc);
        acc = __builtin_elementwise_fma(ws, ws + m2w, acc);
        kmin2 = __builtin_elementwise_min(kmin2, acc);
    }
    float kmin = fmaxf(fminf(kmin2.x, kmin2.y), 0.f);    // clamp once (commutes with min)
    unsigned kbits = __float_as_uint(kmin);              // >=0 -> uint order == float order

    // ---- bound: UB = exact 40th-smallest lane-min via ballot radix (no LDS) ----
    unsigned ub = 0;
    #pragma unroll
    for (int bb = 30; bb >= 0; --bb) {
        unsigned t = ub | (1u << bb);
        int c = (int)__popcll(__ballot(kbits < t));
        if (c < KSEL + 1) ub = t;        // 40th smallest (self included)
    }
    WSYNC();   // cnt init visible (wave-private)

    // ---- compact candidates {d2bits <= ub, m != n}: LDS-atomic slot alloc ----
    #pragma unroll 4
    for (int i = 0; i < 32; ++i) {
        int pr = i * 64 + lane;
        float4 A  = cp4[2 * pr];
        float4 Bv = cp4[2 * pr + 1];
        v2f xs = {A.x,  A.y},  ys = {A.z,  A.w};
        v2f zs = {Bv.x, Bv.y}, ws = {Bv.z, Bv.w};
        v2f acc = __builtin_elementwise_fma(xs, xs + m2x, sqn2);
        acc = __builtin_elementwise_fma(ys, ys + m2y, acc);
        acc = __builtin_elementwise_fma(zs, zs + m2z, acc);
        acc = __builtin_elementwise_fma(ws, ws + m2w, acc);
        acc = __builtin_elementwise_max(acc, zero2);
        int m0 = 2 * pr, m1 = 2 * pr + 1;
        unsigned k0 = __float_as_uint(acc.x);
        unsigned k1 = __float_as_uint(acc.y);
        bool p0 = (k0 <= ub) & (m0 != n);
        bool p1 = (k1 <= ub) & (m1 != n);
        if (p0 || p1) {
            unsigned s = atomicAdd(&cnt_s[wv], (unsigned)((int)p0 + (int)p1));
            if (p0 && s < CAP)
                sel[s] = (((unsigned long long)k0) << 32) | (unsigned)m0;
            unsigned s1 = s + (p0 ? 1u : 0u);
            if (p1 && s1 < CAP)
                sel[s1] = (((unsigned long long)k1) << 32) | (unsigned)m1;
        }
    }
    WSYNC();
    int C = (int)cnt_s[wv];

    if (C <= CAP) {
        // ---- load candidate keys (<=4 chunks of 64) ----
        unsigned kd[4], ki[4];
        #pragma unroll
        for (int c = 0; c < 4; ++c) {
            int s = c * 64 + lane;
            if (s < C) {
                unsigned long long e = sel[s];
                kd[c] = (unsigned)(e >> 32);
                ki[c] = (unsigned)(e & 0xFFFFFFFFu);
            } else { kd[c] = 0xFFFFFFFFu; ki[c] = 0xFFFFFFFFu; }
        }

        // ---- D = exact 39th-smallest d2bits via ballot radix ----
        unsigned D = 0;
        #pragma unroll
        for (int bb = 30; bb >= 0; --bb) {
            unsigned t = D | (1u << bb);
            int c = 0;
            #pragma unroll
            for (int ch = 0; ch < 4; ++ch)
                c += (int)__popcll(__ballot(kd[ch] < t));
            if (c < KSEL) D = t;
        }
        int cless = 0, tiecnt = 0;
        #pragma unroll
        for (int ch = 0; ch < 4; ++ch) {
            cless  += (int)__popcll(__ballot(kd[ch] < D));
            tiecnt += (int)__popcll(__ballot(kd[ch] == D));
        }
        int tneed = KSEL - cless;                 // >= 1; ties to take by lowest index
        unsigned TI = 0xFFFFFFFFu;                // take all ties if they exactly fit
        if (tiecnt > tneed) {                     // rare: resolve by index radix
            unsigned pi = 0;
            #pragma unroll
            for (int bb = 31; bb >= 0; --bb) {
                unsigned t = pi | (1u << bb);
                int c = 0;
                #pragma unroll
                for (int ch = 0; ch < 4; ++ch)
                    c += (int)__popcll(__ballot((kd[ch] == D) && (ki[ch] < t)));
                if (c < tneed) pi = t;
            }
            TI = pi;                              // tneed-th smallest tie index
        }

        // ---- stage selected: weighted features -> fstage[slot][24] ----
        #pragma unroll
        for (int ch = 0; ch < 4; ++ch) {
            bool take = (kd[ch] < D) || ((kd[ch] == D) && (ki[ch] <= TI));
            if (take) {
                unsigned slot = atomicAdd(&cnt2_s[wv], 1u);
                float d2  = __uint_as_float(kd[ch]);
                float wgt = __expf(-10.f * d2);
                const float4* fr = (const float4*)(feats + ((size_t)b * NN + ki[ch]) * PPAD);
                float4 f0 = fr[0], f1 = fr[1], f2 = fr[2], f3 = fr[3], f4 = fr[4], f5 = fr[5];
                float4* row = (float4*)(fstage + slot * PPAD);
                row[0] = make_float4(f0.x * wgt, f0.y * wgt, f0.z * wgt, f0.w * wgt);
                row[1] = make_float4(f1.x * wgt, f1.y * wgt, f1.z * wgt, f1.w * wgt);
                row[2] = make_float4(f2.x * wgt, f2.y * wgt, f2.z * wgt, f2.w * wgt);
                row[3] = make_float4(f3.x * wgt, f3.y * wgt, f3.z * wgt, f3.w * wgt);
                row[4] = make_float4(f4.x * wgt, f4.y * wgt, f4.z * wgt, f4.w * wgt);
                row[5] = make_float4(f5.x * wgt, f5.y * wgt, f5.z * wgt, f5.w * wgt);
            }
        }
    } else {
        // ---- degenerate fallback: exact streaming top-64 over all 4096 ----
        float Lv = INF; int Lm = 0x7FFFFFFF;
        for (int c = 0; c < 64; ++c) {
            int m = c * 64 + lane;
            int pr = m >> 1, sl = m & 1;
            float4 A = cp4[2 * pr], Bv = cp4[2 * pr + 1];
            float cx = sl ? A.y  : A.x,  cy = sl ? A.w  : A.z;
            float cz = sl ? Bv.y : Bv.x, cw = sl ? Bv.w : Bv.z;
            float v = sqn;
            v = fmaf(cx, cx + m2.x, v);
            v = fmaf(cy, cy + m2.y, v);
            v = fmaf(cz, cz + m2.z, v);
            v = fmaf(cw, cw + m2.w, v);
            v = fmaxf(v, 0.f);
            if (m == n) v = INF;
            sort64_pair(v, m, lane);
            if (c == 0) { Lv = v; Lm = m; }
            else        merge64(Lv, Lm, v, m, lane);
        }
        if (lane < KSEL) {
            float wgt = __expf(-10.f * Lv);
            const float4* fr = (const float4*)(feats + ((size_t)b * NN + Lm) * PPAD);
            float4 f0 = fr[0], f1 = fr[1], f2 = fr[2], f3 = fr[3], f4 = fr[4], f5 = fr[5];
            float4* row = (float4*)(fstage + lane * PPAD);
            row[0] = make_float4(f0.x * wgt, f0.y * wgt, f0.z * wgt, f0.w * wgt);
            row[1] = make_float4(f1.x * wgt, f1.y * wgt, f1.z * wgt, f1.w * wgt);
            row[2] = make_float4(f2.x * wgt, f2.y * wgt, f2.z * wgt, f2.w * wgt);
            row[3] = make_float4(f3.x * wgt, f3.y * wgt, f3.z * wgt, f3.w * wgt);
            row[4] = make_float4(f4.x * wgt, f4.y * wgt, f4.z * wgt, f4.w * wgt);
            row[5] = make_float4(f5.x * wgt, f5.y * wgt, f5.z * wgt, f5.w * wgt);
        }
    }
    WSYNC();

    // ---- max / mean over 39 neighbors (lanes 0..21) ----
    if (lane < PP) {
        float mx = NEGINF, sm = 0.f;
        for (int k = 0; k < KSEL; ++k) {
            float v = fstage[k * PPAD + lane];
            mx = fmaxf(mx, v);
            sm += v;
        }
        agg[lane]      = mx;
        agg[PP + lane] = sm * (1.f / (float)KSEL);
    }
    WSYNC();

    // ---- epilogue: out = tanh([x | max | mean] @ Wo + bo), fast tanh ----
    if (lane < FOUT) {
        const float* xr = x + (size_t)q * FIN;
        float acc = bo[lane];
        #pragma unroll
        for (int f = 0; f < FIN; ++f)
            acc = fmaf(xr[f], Wo[f * FOUT + lane], acc);
        #pragma unroll
        for (int f = 0; f < 2 * PP; ++f)
            acc = fmaf(agg[f], Wo[(FIN + f) * FOUT + lane], acc);
        float e = __expf(2.f * acc);
        float r = __builtin_amdgcn_rcpf(e + 1.f);
        out[(size_t)q * FOUT + lane] = fmaf(-2.f, r, 1.f);
    }
}

extern "C" void kernel_launch(void* const* d_in, const int* in_sizes, int n_in,
                              void* d_out, int out_size, void* d_ws, size_t ws_size,
                              hipStream_t stream) {
    const float* x  = (const float*)d_in[0];
    const float* Wf = (const float*)d_in[1];
    const float* bf = (const float*)d_in[2];
    const float* Ws = (const float*)d_in[3];
    const float* bs = (const float*)d_in[4];
    const float* Wo = (const float*)d_in[5];
    const float* bo = (const float*)d_in[6];
    float* outp = (float*)d_out;

    float* ws      = (float*)d_ws;
    float* coords4 = ws;                      // 32768*4  = 131072 floats
    float* cpair   = ws + 131072;             // 32768*4  = 131072 floats (pair-SoA)
    float* feats   = ws + 262144;             // 32768*24 = 786432 floats

    gn_pre<<<32768 / 256, 256, 0, stream>>>(x, Wf, bf, Ws, bs, coords4, cpair, feats);
    gn_main<<<32768 / WPB, WPB * 64, 0, stream>>>(x, Wo, bo, coords4, cpair, feats, outp);
}